// Round 4
// baseline (97.195 us; speedup 1.0000x reference)
//
#include <hip/hip_runtime.h>

// StochasticPool2d: x (B=32, C=64, H=224, W=224) f32.
// out[b,c,i,j] = max 2x2 window (zero-padded right/bottom) of x at
// (h_off[i]+2i, w_off[j]+2j)  -> (32,64,112,112)
//
// 8 outputs per thread (two adjacent float4 output groups): needs floats
// [16*j8 .. 16*j8+16] of rows h and h+1 -> 10 float4 loads, 17 vertical
// maxes, 8 horizontal selects, two coalesced float4 stores. Grid-stride,
// no LDS, no barriers.

#define H 224
#define W 224
#define NH 112
#define NW 112
#define J8 14  // NW/8 groups per output row

__global__ __launch_bounds__(256) void spool_kernel(
    const float* __restrict__ x,
    const int* __restrict__ h_off,
    const int* __restrict__ w_off,
    float* __restrict__ out,
    int total8) {
  const int stride = gridDim.x * blockDim.x;
  for (int t = blockIdx.x * blockDim.x + threadIdx.x; t < total8; t += stride) {
    const int j8 = t % J8;
    const int r = t / J8;      // plane*NH + i
    const int i = r % NH;
    const int plane = r / NH;  // b*C + c

    const int h = h_off[i] + 2 * i;  // [0, 223]
    const bool has1 = (h + 1 < H);
    const bool hasR = (j8 != J8 - 1);

    const float4* p0 = (const float4*)(x + ((size_t)plane * H + h) * W) + 4 * j8;
    const float4* p1 = has1 ? p0 + (W / 4) : p0;  // safe in-bounds fallback

    float4 a0 = p0[0], a1 = p0[1], a2 = p0[2], a3 = p0[3];
    float4 a4 = p0[hasR ? 4 : 3];
    float4 b0 = p1[0], b1 = p1[1], b2 = p1[2], b3 = p1[3];
    float4 b4 = p1[hasR ? 4 : 3];

    // vertical max with bottom zero-pad
    float v0  = fmaxf(a0.x, has1 ? b0.x : 0.f);
    float v1  = fmaxf(a0.y, has1 ? b0.y : 0.f);
    float v2  = fmaxf(a0.z, has1 ? b0.z : 0.f);
    float v3  = fmaxf(a0.w, has1 ? b0.w : 0.f);
    float v4  = fmaxf(a1.x, has1 ? b1.x : 0.f);
    float v5  = fmaxf(a1.y, has1 ? b1.y : 0.f);
    float v6  = fmaxf(a1.z, has1 ? b1.z : 0.f);
    float v7  = fmaxf(a1.w, has1 ? b1.w : 0.f);
    float v8  = fmaxf(a2.x, has1 ? b2.x : 0.f);
    float v9  = fmaxf(a2.y, has1 ? b2.y : 0.f);
    float v10 = fmaxf(a2.z, has1 ? b2.z : 0.f);
    float v11 = fmaxf(a2.w, has1 ? b2.w : 0.f);
    float v12 = fmaxf(a3.x, has1 ? b3.x : 0.f);
    float v13 = fmaxf(a3.y, has1 ? b3.y : 0.f);
    float v14 = fmaxf(a3.z, has1 ? b3.z : 0.f);
    float v15 = fmaxf(a3.w, has1 ? b3.w : 0.f);
    float v16 = fmaxf(hasR ? a4.x : 0.f, (has1 && hasR) ? b4.x : 0.f);

    // horizontal max, offset bit from w_off (0 or 1), outputs j = 8*j8 + k
    const int4 wo0 = *((const int4*)w_off + 2 * j8);
    const int4 wo1 = *((const int4*)w_off + 2 * j8 + 1);
    float o0 = wo0.x ? fmaxf(v1,  v2)  : fmaxf(v0,  v1);
    float o1 = wo0.y ? fmaxf(v3,  v4)  : fmaxf(v2,  v3);
    float o2 = wo0.z ? fmaxf(v5,  v6)  : fmaxf(v4,  v5);
    float o3 = wo0.w ? fmaxf(v7,  v8)  : fmaxf(v6,  v7);
    float o4 = wo1.x ? fmaxf(v9,  v10) : fmaxf(v8,  v9);
    float o5 = wo1.y ? fmaxf(v11, v12) : fmaxf(v10, v11);
    float o6 = wo1.z ? fmaxf(v13, v14) : fmaxf(v12, v13);
    float o7 = wo1.w ? fmaxf(v15, v16) : fmaxf(v14, v15);

    float4* o = (float4*)out + 2 * (size_t)t;  // float4 group r*28 + 2*j8 == 2t
    o[0] = make_float4(o0, o1, o2, o3);
    o[1] = make_float4(o4, o5, o6, o7);
  }
}

extern "C" void kernel_launch(void* const* d_in, const int* in_sizes, int n_in,
                              void* d_out, int out_size, void* d_ws, size_t ws_size,
                              hipStream_t stream) {
  const float* x = (const float*)d_in[0];
  const int* h_off = (const int*)d_in[1];
  const int* w_off = (const int*)d_in[2];
  float* out = (float*)d_out;

  const int total8 = out_size / 8;  // 3,211,264
  const int block = 256;
  const int grid = 2048;  // grid-stride; ~6.1 iters/thread
  spool_kernel<<<grid, block, 0, stream>>>(x, h_off, w_off, out, total8);
}

// Round 6
// 83.940 us; speedup vs baseline: 1.1579x; 1.1579x over previous
//
#include <hip/hip_runtime.h>

// StochasticPool2d: x (B=32, C=64, H=224, W=224) f32.
// out[b,c,i,j] = max 2x2 window (zero-padded right/bottom) of x at
// (h_off[i]+2i, w_off[j]+2j)  -> (32,64,112,112)
//
// R3 structure (best so far: 91.8 us): 4 outputs/thread, 6 float4 loads,
// grid-stride, no LDS. R5 delta: nontemporal stores (native clang vector
// type this time — __builtin_nontemporal_store rejects HIP_vector_type).

#define H 224
#define W 224
#define NH 112
#define NW 112
#define J4 28  // NW/4 float4-groups per output row

typedef float f32x4 __attribute__((ext_vector_type(4)));

__global__ __launch_bounds__(256) void spool_kernel(
    const float* __restrict__ x,
    const int* __restrict__ h_off,
    const int* __restrict__ w_off,
    float* __restrict__ out,
    int total4) {
  const int stride = gridDim.x * blockDim.x;
  for (int t = blockIdx.x * blockDim.x + threadIdx.x; t < total4; t += stride) {
    const int j4 = t % J4;
    const int r = t / J4;      // plane*NH + i
    const int i = r % NH;
    const int plane = r / NH;  // b*C + c

    const int h = h_off[i] + 2 * i;  // [0, 223]
    const bool has1 = (h + 1 < H);
    const bool hasR = (j4 != J4 - 1);

    const float4* p0 = (const float4*)(x + ((size_t)plane * H + h) * W) + 2 * j4;
    const float4* p1 = has1 ? p0 + (W / 4) : p0;  // safe in-bounds fallback

    float4 a0 = p0[0];
    float4 a1 = p0[1];
    float4 a2 = p0[hasR ? 2 : 1];
    float4 b0 = p1[0];
    float4 b1 = p1[1];
    float4 b2 = p1[hasR ? 2 : 1];

    // vertical max v[m] = max(x[h][8j4+m], x[h+1][8j4+m] or pad 0)
    float v0 = fmaxf(a0.x, has1 ? b0.x : 0.f);
    float v1 = fmaxf(a0.y, has1 ? b0.y : 0.f);
    float v2 = fmaxf(a0.z, has1 ? b0.z : 0.f);
    float v3 = fmaxf(a0.w, has1 ? b0.w : 0.f);
    float v4 = fmaxf(a1.x, has1 ? b1.x : 0.f);
    float v5 = fmaxf(a1.y, has1 ? b1.y : 0.f);
    float v6 = fmaxf(a1.z, has1 ? b1.z : 0.f);
    float v7 = fmaxf(a1.w, has1 ? b1.w : 0.f);
    float v8 = fmaxf(hasR ? a2.x : 0.f, (has1 && hasR) ? b2.x : 0.f);

    // horizontal max, offset bit from w_off (0 or 1)
    const int4 wo = *((const int4*)w_off + j4);
    float o0 = wo.x ? fmaxf(v1, v2) : fmaxf(v0, v1);
    float o1 = wo.y ? fmaxf(v3, v4) : fmaxf(v2, v3);
    float o2 = wo.z ? fmaxf(v5, v6) : fmaxf(v4, v5);
    float o3 = wo.w ? fmaxf(v7, v8) : fmaxf(v6, v7);

    f32x4 res = {o0, o1, o2, o3};
    __builtin_nontemporal_store(res, (f32x4*)out + t);
  }
}

extern "C" void kernel_launch(void* const* d_in, const int* in_sizes, int n_in,
                              void* d_out, int out_size, void* d_ws, size_t ws_size,
                              hipStream_t stream) {
  const float* x = (const float*)d_in[0];
  const int* h_off = (const int*)d_in[1];
  const int* w_off = (const int*)d_in[2];
  float* out = (float*)d_out;

  const int total4 = out_size / 4;  // 6,422,528 float4 outputs
  const int block = 256;
  const int grid = 2048;  // grid-stride; ~12.25 iters/thread
  spool_kernel<<<grid, block, 0, stream>>>(x, h_off, w_off, out, total4);
}

// Round 7
// 81.483 us; speedup vs baseline: 1.1928x; 1.0302x over previous
//
#include <hip/hip_runtime.h>

// StochasticPool2d: x (B=32, C=64, H=224, W=224) f32.
// out[b,c,i,j] = max 2x2 window (zero-padded right/bottom) of x at
// (h_off[i]+2i, w_off[j]+2j)  -> (32,64,112,112)
//
// R6 (83.9 us): 4 outputs/thread, 6 float4 loads, NT float4 store,
// grid-stride 2048 blocks. R7 delta: grid 2048 -> 8192 (3.06 iters/thread)
// to test whether wave-level parallelism is the remaining 14% to the
// 73.5-us traffic floor.

#define H 224
#define W 224
#define NH 112
#define NW 112
#define J4 28  // NW/4 float4-groups per output row

typedef float f32x4 __attribute__((ext_vector_type(4)));

__global__ __launch_bounds__(256) void spool_kernel(
    const float* __restrict__ x,
    const int* __restrict__ h_off,
    const int* __restrict__ w_off,
    float* __restrict__ out,
    int total4) {
  const int stride = gridDim.x * blockDim.x;
  for (int t = blockIdx.x * blockDim.x + threadIdx.x; t < total4; t += stride) {
    const int j4 = t % J4;
    const int r = t / J4;      // plane*NH + i
    const int i = r % NH;
    const int plane = r / NH;  // b*C + c

    const int h = h_off[i] + 2 * i;  // [0, 223]
    const bool has1 = (h + 1 < H);
    const bool hasR = (j4 != J4 - 1);

    const float4* p0 = (const float4*)(x + ((size_t)plane * H + h) * W) + 2 * j4;
    const float4* p1 = has1 ? p0 + (W / 4) : p0;  // safe in-bounds fallback

    float4 a0 = p0[0];
    float4 a1 = p0[1];
    float4 a2 = p0[hasR ? 2 : 1];
    float4 b0 = p1[0];
    float4 b1 = p1[1];
    float4 b2 = p1[hasR ? 2 : 1];

    // vertical max v[m] = max(x[h][8j4+m], x[h+1][8j4+m] or pad 0)
    float v0 = fmaxf(a0.x, has1 ? b0.x : 0.f);
    float v1 = fmaxf(a0.y, has1 ? b0.y : 0.f);
    float v2 = fmaxf(a0.z, has1 ? b0.z : 0.f);
    float v3 = fmaxf(a0.w, has1 ? b0.w : 0.f);
    float v4 = fmaxf(a1.x, has1 ? b1.x : 0.f);
    float v5 = fmaxf(a1.y, has1 ? b1.y : 0.f);
    float v6 = fmaxf(a1.z, has1 ? b1.z : 0.f);
    float v7 = fmaxf(a1.w, has1 ? b1.w : 0.f);
    float v8 = fmaxf(hasR ? a2.x : 0.f, (has1 && hasR) ? b2.x : 0.f);

    // horizontal max, offset bit from w_off (0 or 1)
    const int4 wo = *((const int4*)w_off + j4);
    float o0 = wo.x ? fmaxf(v1, v2) : fmaxf(v0, v1);
    float o1 = wo.y ? fmaxf(v3, v4) : fmaxf(v2, v3);
    float o2 = wo.z ? fmaxf(v5, v6) : fmaxf(v4, v5);
    float o3 = wo.w ? fmaxf(v7, v8) : fmaxf(v6, v7);

    f32x4 res = {o0, o1, o2, o3};
    __builtin_nontemporal_store(res, (f32x4*)out + t);
  }
}

extern "C" void kernel_launch(void* const* d_in, const int* in_sizes, int n_in,
                              void* d_out, int out_size, void* d_ws, size_t ws_size,
                              hipStream_t stream) {
  const float* x = (const float*)d_in[0];
  const int* h_off = (const int*)d_in[1];
  const int* w_off = (const int*)d_in[2];
  float* out = (float*)d_out;

  const int total4 = out_size / 4;  // 6,422,528 float4 outputs
  const int block = 256;
  const int grid = 8192;  // grid-stride; ~3.06 iters/thread
  spool_kernel<<<grid, block, 0, stream>>>(x, h_off, w_off, out, total4);
}

// Round 8
// 79.523 us; speedup vs baseline: 1.2222x; 1.0247x over previous
//
#include <hip/hip_runtime.h>

// StochasticPool2d: x (B=32, C=64, H=224, W=224) f32.
// out[b,c,i,j] = max 2x2 window (zero-padded right/bottom) of x at
// (h_off[i]+2i, w_off[j]+2j)  -> (32,64,112,112)
//
// R7 (81.5 us): 4 outputs/thread, 6 float4 loads, NT store, grid-stride 8192.
// R8 delta: exact-fit one-shot grid — 25088 blocks x 256 threads ==
// 6,422,528 == total4 exactly. No loop, no bounds check, no ragged tail.

#define H 224
#define W 224
#define NH 112
#define NW 112
#define J4 28  // NW/4 float4-groups per output row

typedef float f32x4 __attribute__((ext_vector_type(4)));

__global__ __launch_bounds__(256) void spool_kernel(
    const float* __restrict__ x,
    const int* __restrict__ h_off,
    const int* __restrict__ w_off,
    float* __restrict__ out) {
  const int t = blockIdx.x * blockDim.x + threadIdx.x;  // == output float4 id

  const int j4 = t % J4;
  const int r = t / J4;      // plane*NH + i
  const int i = r % NH;
  const int plane = r / NH;  // b*C + c

  const int h = h_off[i] + 2 * i;  // [0, 223]
  const bool has1 = (h + 1 < H);
  const bool hasR = (j4 != J4 - 1);

  const float4* p0 = (const float4*)(x + ((size_t)plane * H + h) * W) + 2 * j4;
  const float4* p1 = has1 ? p0 + (W / 4) : p0;  // safe in-bounds fallback

  float4 a0 = p0[0];
  float4 a1 = p0[1];
  float4 a2 = p0[hasR ? 2 : 1];
  float4 b0 = p1[0];
  float4 b1 = p1[1];
  float4 b2 = p1[hasR ? 2 : 1];

  // vertical max v[m] = max(x[h][8j4+m], x[h+1][8j4+m] or pad 0)
  float v0 = fmaxf(a0.x, has1 ? b0.x : 0.f);
  float v1 = fmaxf(a0.y, has1 ? b0.y : 0.f);
  float v2 = fmaxf(a0.z, has1 ? b0.z : 0.f);
  float v3 = fmaxf(a0.w, has1 ? b0.w : 0.f);
  float v4 = fmaxf(a1.x, has1 ? b1.x : 0.f);
  float v5 = fmaxf(a1.y, has1 ? b1.y : 0.f);
  float v6 = fmaxf(a1.z, has1 ? b1.z : 0.f);
  float v7 = fmaxf(a1.w, has1 ? b1.w : 0.f);
  float v8 = fmaxf(hasR ? a2.x : 0.f, (has1 && hasR) ? b2.x : 0.f);

  // horizontal max, offset bit from w_off (0 or 1)
  const int4 wo = *((const int4*)w_off + j4);
  float o0 = wo.x ? fmaxf(v1, v2) : fmaxf(v0, v1);
  float o1 = wo.y ? fmaxf(v3, v4) : fmaxf(v2, v3);
  float o2 = wo.z ? fmaxf(v5, v6) : fmaxf(v4, v5);
  float o3 = wo.w ? fmaxf(v7, v8) : fmaxf(v6, v7);

  f32x4 res = {o0, o1, o2, o3};
  __builtin_nontemporal_store(res, (f32x4*)out + t);
}

extern "C" void kernel_launch(void* const* d_in, const int* in_sizes, int n_in,
                              void* d_out, int out_size, void* d_ws, size_t ws_size,
                              hipStream_t stream) {
  const float* x = (const float*)d_in[0];
  const int* h_off = (const int*)d_in[1];
  const int* w_off = (const int*)d_in[2];
  float* out = (float*)d_out;

  const int total4 = out_size / 4;      // 6,422,528
  const int block = 256;
  const int grid = total4 / block;      // 25088, exact
  spool_kernel<<<grid, block, 0, stream>>>(x, h_off, w_off, out);
}